// Round 2
// baseline (769.423 us; speedup 1.0000x reference)
//
#include <hip/hip_runtime.h>
#include <math.h>

#define B_    32
#define REP_  1024
#define NV_   504
#define NR_   190
#define NN_   11538
#define MR_   6
#define HID_  32
#define NH_   4
#define HD_   8
#define MAXN_ 512

// d_out offsets (floats)
#define O_VP   32768
#define O_RN   48896
#define O_NORM 70199936
#define O_VMAX 70199968
#define O_MAXI 70216096

// ws offsets (floats)
#define W_REPT  0
#define W_WT    32768
#define W_PN    401984      // 8 * 194560
#define W_PV    1958464     // 8 * 16128
#define W_N0    2087488
#define W_HOB   2282048     // ho buffer B (194560)
#define W_HOA   2476608     // ho buffer A (194560)
#define W_MARG  2671168
#define W_RMAX  2677248
#define W_RMAXI 2683328     // int storage
#define W_WC    2689408     // 2 * (3072 + 96) combined attn-in weights

typedef float vf4 __attribute__((ext_vector_type(4)));
typedef float vf2 __attribute__((ext_vector_type(2)));

// ---------------------------------------------------------------- transposes
__global__ __launch_bounds__(256) void k_tr_rep(const float* __restrict__ rep,
                                                float* __restrict__ repT) {
    int gid = blockIdx.x * 256 + threadIdx.x;   // 32768 exact
    int b = gid & 31, k = gid >> 5;
    repT[gid] = rep[b * REP_ + k];
}

// blocks 0..360: 32x32 LDS tile transpose Wn (32 x 11538) -> Wt (11538 x 32)
// block 361: precompute combined attn weights for layers 2,3:
//   Wc[row][d] = sum_e iw[row][e] * ow[e][d];  bc[row] = iw[row]·ob + ib[row]
__global__ __launch_bounds__(256) void k_pre(const float* __restrict__ Wn,
                                             float* __restrict__ Wt,
                                             const float* __restrict__ ainw,
                                             const float* __restrict__ ainb,
                                             const float* __restrict__ aoutw,
                                             const float* __restrict__ aoutb,
                                             float* __restrict__ wc) {
    __shared__ float t[32][33];
    int tid = threadIdx.x;
    if (blockIdx.x < 361) {
        int n0 = blockIdx.x * 32;
        #pragma unroll
        for (int p = 0; p < 4; p++) {
            int idx = p * 256 + tid;
            int k = idx >> 5, n = idx & 31;
            int nn = n0 + n;
            t[k][n] = (nn < NN_) ? Wn[(size_t)k * NN_ + nn] : 0.f;
        }
        __syncthreads();
        #pragma unroll
        for (int p = 0; p < 4; p++) {
            int idx = p * 256 + tid;
            int n = idx >> 5, k = idx & 31;
            int nn = n0 + n;
            if (nn < NN_) Wt[nn * 32 + k] = t[k][n];
        }
    } else {
        #pragma unroll 1
        for (int layer = 0; layer < 2; layer++) {
            const float* iw  = ainw + (layer + 1) * 3072;   // in_w of next layer
            const float* ib  = ainb + (layer + 1) * 96;
            const float* ow  = aoutw + layer * 1024;        // out_w of this layer
            const float* obv = aoutb + layer * 32;
            float* W = wc + layer * 3168;
            for (int idx = tid; idx < 3072; idx += 256) {
                int row = idx >> 5, d = idx & 31;
                float s = 0.f;
                #pragma unroll
                for (int e = 0; e < 32; e++) s += iw[row * 32 + e] * ow[e * 32 + d];
                W[idx] = s;
            }
            if (tid < 96) {
                float s = ib[tid];
                #pragma unroll
                for (int e = 0; e < 32; e++) s += iw[tid * 32 + e] * obv[e];
                W[3072 + tid] = s;
            }
        }
    }
}

// ------------------------------------------------- rep GEMMs (k-split partials)
// bx < 95 : node columns (6080);  bx >= 95 : v_potential columns (504)
__global__ __launch_bounds__(256) void k_gemm(const float* __restrict__ Wr,
                                              const float* __restrict__ Wv,
                                              const float4* __restrict__ repT4,
                                              float* __restrict__ pn,
                                              float* __restrict__ pv) {
    int bx = blockIdx.x;
    int lane = threadIdx.x & 63;
    int bg = threadIdx.x >> 6;
    int k0 = blockIdx.y * 128;
    int rbase = k0 * 8 + bg * 2;
    float acc[8] = {0.f,0.f,0.f,0.f,0.f,0.f,0.f,0.f};
    if (bx < 95) {
        int c = bx * 64 + lane;
        const float* w = Wr + (size_t)k0 * 6080 + c;
        #pragma unroll 4
        for (int k = 0; k < 128; k++) {
            float wv = w[(size_t)k * 6080];
            float4 ra = repT4[rbase + k * 8];
            float4 rb = repT4[rbase + k * 8 + 1];
            acc[0] += ra.x * wv; acc[1] += ra.y * wv; acc[2] += ra.z * wv; acc[3] += ra.w * wv;
            acc[4] += rb.x * wv; acc[5] += rb.y * wv; acc[6] += rb.z * wv; acc[7] += rb.w * wv;
        }
        size_t base = (size_t)blockIdx.y * 194560 + (size_t)(bg * 8) * 6080 + c;
        #pragma unroll
        for (int i = 0; i < 8; i++) pn[base + (size_t)i * 6080] = acc[i];
    } else {
        int c = (bx - 95) * 64 + lane;
        if (c >= NV_) return;
        const float* w = Wv + (size_t)k0 * NV_ + c;
        #pragma unroll 4
        for (int k = 0; k < 128; k++) {
            float wv = w[(size_t)k * NV_];
            float4 ra = repT4[rbase + k * 8];
            float4 rb = repT4[rbase + k * 8 + 1];
            acc[0] += ra.x * wv; acc[1] += ra.y * wv; acc[2] += ra.z * wv; acc[3] += ra.w * wv;
            acc[4] += rb.x * wv; acc[5] += rb.y * wv; acc[6] += rb.z * wv; acc[7] += rb.w * wv;
        }
        size_t base = (size_t)blockIdx.y * 16128 + (size_t)(bg * 8) * NV_ + c;
        #pragma unroll
        for (int i = 0; i < 8; i++) pv[base + (size_t)i * NV_] = acc[i];
    }
}

__global__ __launch_bounds__(256) void k_reduce(const float* __restrict__ pn,
                                                const float* __restrict__ pv,
                                                const float* __restrict__ br,
                                                const float* __restrict__ bv,
                                                float* __restrict__ node0,
                                                float* __restrict__ vpot) {
    int bid = blockIdx.x, tid = threadIdx.x;
    if (bid < 760) {
        int gid = bid * 256 + tid;                 // enumerates [b][c], c<6080
        int b = gid / 6080, c = gid - b * 6080;
        float s = br[c];
        #pragma unroll
        for (int kz = 0; kz < 8; kz++) s += pn[kz * 194560 + gid];
        node0[(c >> 5) * 1024 + b * 32 + (c & 31)] = s;
    } else {
        int gid = (bid - 760) * 256 + tid;         // enumerates [b][v], v<504
        int v = gid % NV_;
        float s = bv[v];
        #pragma unroll
        for (int kz = 0; kz < 8; kz++) s += pv[kz * 16128 + gid];
        vpot[gid] = s;
    }
}

// ---------------------------------------------------------------- attention
// One block per (b,h). Input xin is [l][b][e] (either node0 or previous ho);
// winw/winb are either the raw layer-0 in-proj or the folded (in·out) weights,
// so the out-projection kernels disappear entirely.
__global__ __launch_bounds__(256) void k_attn(const float* __restrict__ xin,
                                              const float* __restrict__ winw,
                                              const float* __restrict__ winb,
                                              float* __restrict__ ho) {
    int b = blockIdx.x >> 2, h = blockIdx.x & 3;
    int tid = threadIdx.x;
    __shared__ __align__(16) float qs[192 * 12];
    __shared__ __align__(16) float ks[192 * 12];
    __shared__ __align__(16) float vs[192 * 12];
    __shared__ __align__(16) float pmS[4 * 192];
    __shared__ __align__(16) float psS[4 * 192];
    __shared__ __align__(16) float poS[4 * 192 * 8];

    if (tid < NR_) {
        const float* xr = xin + tid * 1024 + b * 32;
        float4 xv[8];
        #pragma unroll
        for (int q = 0; q < 8; q++) xv[q] = *(const float4*)(xr + q * 4);
        #pragma unroll 1
        for (int part = 0; part < 3; part++) {
            float* dst = (part == 0) ? qs : (part == 1) ? ks : vs;
            #pragma unroll 1
            for (int jj = 0; jj < 8; jj++) {
                int row = part * 32 + h * 8 + jj;      // wave-uniform
                const float* wr = winw + row * 32;
                float s = winb[row];
                #pragma unroll
                for (int q = 0; q < 8; q++) {
                    s += xv[q].x * wr[q*4+0] + xv[q].y * wr[q*4+1] +
                         xv[q].z * wr[q*4+2] + xv[q].w * wr[q*4+3];
                }
                dst[tid * 12 + jj] = s;
            }
        }
    }
    __syncthreads();

    int wave = tid >> 6, lane = tid & 63;
    int m0 = wave * 48;
    int m1 = (m0 + 48 < NR_) ? (m0 + 48) : NR_;
    float4 qa[3], qb[3];
    #pragma unroll
    for (int i = 0; i < 3; i++) {
        int l = lane + 64 * i;
        if (l < NR_) {
            qa[i] = *(const float4*)&qs[l * 12];
            qb[i] = *(const float4*)&qs[l * 12 + 4];
        } else {
            qa[i] = make_float4(0.f,0.f,0.f,0.f);
            qb[i] = make_float4(0.f,0.f,0.f,0.f);
        }
    }
    float mM[3] = {-INFINITY, -INFINITY, -INFINITY};
    float sS[3] = {0.f, 0.f, 0.f};
    float o[3][8];
    #pragma unroll
    for (int i = 0; i < 3; i++)
        #pragma unroll
        for (int d = 0; d < 8; d++) o[i][d] = 0.f;
    const float scale = 0.3535533905932738f;
    for (int mm = m0; mm < m1; mm++) {
        float4 ka = *(const float4*)&ks[mm * 12];
        float4 kb = *(const float4*)&ks[mm * 12 + 4];
        float4 va = *(const float4*)&vs[mm * 12];
        float4 vb = *(const float4*)&vs[mm * 12 + 4];
        #pragma unroll
        for (int i = 0; i < 3; i++) {
            float sc = (qa[i].x*ka.x + qa[i].y*ka.y + qa[i].z*ka.z + qa[i].w*ka.w +
                        qb[i].x*kb.x + qb[i].y*kb.y + qb[i].z*kb.z + qb[i].w*kb.w) * scale;
            if (sc > mM[i]) {
                float al = __expf(mM[i] - sc);   // exp(-inf)=0 on first hit
                sS[i] = sS[i] * al + 1.f;
                mM[i] = sc;
                o[i][0] = o[i][0]*al + va.x; o[i][1] = o[i][1]*al + va.y;
                o[i][2] = o[i][2]*al + va.z; o[i][3] = o[i][3]*al + va.w;
                o[i][4] = o[i][4]*al + vb.x; o[i][5] = o[i][5]*al + vb.y;
                o[i][6] = o[i][6]*al + vb.z; o[i][7] = o[i][7]*al + vb.w;
            } else {
                float p = __expf(sc - mM[i]);
                sS[i] += p;
                o[i][0] += p*va.x; o[i][1] += p*va.y; o[i][2] += p*va.z; o[i][3] += p*va.w;
                o[i][4] += p*vb.x; o[i][5] += p*vb.y; o[i][6] += p*vb.z; o[i][7] += p*vb.w;
            }
        }
    }
    #pragma unroll
    for (int i = 0; i < 3; i++) {
        int slot = wave * 192 + lane + 64 * i;
        pmS[slot] = mM[i];
        psS[slot] = sS[i];
        *(float4*)&poS[slot * 8]     = make_float4(o[i][0], o[i][1], o[i][2], o[i][3]);
        *(float4*)&poS[slot * 8 + 4] = make_float4(o[i][4], o[i][5], o[i][6], o[i][7]);
    }
    __syncthreads();

    if (tid < NR_) {
        float M = pmS[tid], S = psS[tid];
        float4 oa = *(const float4*)&poS[tid * 8];
        float4 ob = *(const float4*)&poS[tid * 8 + 4];
        #pragma unroll
        for (int w = 1; w < 4; w++) {
            int slot = w * 192 + tid;
            float m2 = pmS[slot], s2 = psS[slot];
            float4 pa = *(const float4*)&poS[slot * 8];
            float4 pb = *(const float4*)&poS[slot * 8 + 4];
            if (m2 > M) {
                float al = __expf(M - m2);
                S = S * al + s2;
                oa.x = oa.x*al + pa.x; oa.y = oa.y*al + pa.y; oa.z = oa.z*al + pa.z; oa.w = oa.w*al + pa.w;
                ob.x = ob.x*al + pb.x; ob.y = ob.y*al + pb.y; ob.z = ob.z*al + pb.z; ob.w = ob.w*al + pb.w;
                M = m2;
            } else {
                float p = __expf(m2 - M);
                S += s2 * p;
                oa.x += p*pa.x; oa.y += p*pa.y; oa.z += p*pa.z; oa.w += p*pa.w;
                ob.x += p*pb.x; ob.y += p*pb.y; ob.z += p*pb.z; ob.w += p*pb.w;
            }
        }
        float inv = 1.f / S;
        float* hp = ho + tid * 1024 + b * 32 + h * 8;
        *(float4*)hp       = make_float4(oa.x*inv, oa.y*inv, oa.z*inv, oa.w*inv);
        *(float4*)(hp + 4) = make_float4(ob.x*inv, ob.y*inv, ob.z*inv, ob.w*inv);
    }
}

// ----------------------------------------- fused back-end: rnpot + grouped
// Final out-proj (layer 3) is folded in: each block recomputes its node tile
// from ho3 and ow3 (transposed in LDS).
// grid (380, 24): y<23 -> rn_potential tiles (16 rows x 512 cols);
//                 y==23, x<190 -> grouped gather for role l=x.
// 16x512 tile + acc[4][8] + __launch_bounds__(256,4) => VGPR<=128, 4 blk/CU,
// doubling latency-hiding vs the old 256-VGPR 2 blk/CU version.
__global__ __launch_bounds__(256, 4) void k_big(const float* __restrict__ ho3,
                                                const float* __restrict__ ow3,
                                                const float* __restrict__ ob3,
                                                const float* __restrict__ Wn,
                                                const float* __restrict__ bn,
                                                const float* __restrict__ Wt,
                                                const int* __restrict__ rni,
                                                float* __restrict__ out_rn,
                                                float* __restrict__ marg,
                                                float* __restrict__ rmax,
                                                int* __restrict__ rmaxi) {
    if (blockIdx.y == 23 && blockIdx.x >= 190) return;
    int tid = threadIdx.x;
    __shared__ float owT[1024];       // owT[d*32+h] = ow3[h*32+d]
    __shared__ float As[512];         // node tile [16 rows][32 h]
    __shared__ float pm[256], psum[256];
    __shared__ int   pj[256];

    for (int i = tid; i < 1024; i += 256) {
        int d = i >> 5, hh = i & 31;
        owT[i] = ow3[hh * 32 + d];
    }

    if (blockIdx.y < 23) {
        int bx = blockIdx.x;              // 0..379
        int l  = bx >> 1;
        int bhalf = (bx & 1) * 16;
        // ---------- node tile recompute (128 threads): As[bl][h] = ho3·ow3 + ob3
        float4 hv[8];
        int bl = tid >> 3, hq = tid & 7;
        if (tid < 128) {
            const float4* hp = (const float4*)&ho3[(size_t)l * 1024 + (bhalf + bl) * 32];
            #pragma unroll
            for (int q = 0; q < 8; q++) hv[q] = hp[q];
        }
        __syncthreads();
        if (tid < 128) {
            float4 a = *(const float4*)&ob3[hq * 4];
            #pragma unroll
            for (int dq = 0; dq < 8; dq++) {
                float4 h4 = hv[dq];
                float4 w0 = *(const float4*)&owT[(dq*4+0)*32 + hq*4];
                float4 w1 = *(const float4*)&owT[(dq*4+1)*32 + hq*4];
                float4 w2 = *(const float4*)&owT[(dq*4+2)*32 + hq*4];
                float4 w3 = *(const float4*)&owT[(dq*4+3)*32 + hq*4];
                a.x += h4.x*w0.x + h4.y*w1.x + h4.z*w2.x + h4.w*w3.x;
                a.y += h4.x*w0.y + h4.y*w1.y + h4.z*w2.y + h4.w*w3.y;
                a.z += h4.x*w0.z + h4.y*w1.z + h4.z*w2.z + h4.w*w3.z;
                a.w += h4.x*w0.w + h4.y*w1.w + h4.z*w2.w + h4.w*w3.w;
            }
            *(float4*)&As[bl * 32 + hq * 4] = a;
        }
        __syncthreads();

        // ---------- 16 x 512 GEMM tile
        int t0 = bx * 16;
        int c0 = blockIdx.y * 512;
        int wave = tid >> 6, lane = tid & 63;
        int r0 = wave * 4;                // local row base (0..12)
        int c = c0 + lane * 8;
        int rem = NN_ - c;
        if (rem <= 0) return;
        if (rem >= 8) {
            float acc[4][8];
            #pragma unroll
            for (int r = 0; r < 4; r++)
                #pragma unroll
                for (int q = 0; q < 8; q++) acc[r][q] = 0.f;
            #pragma unroll 1
            for (int g = 0; g < 8; g++) {
                float4 av[4];
                #pragma unroll
                for (int r = 0; r < 4; r++)
                    av[r] = *(const float4*)&As[(r0 + r) * 32 + g * 4];
                #pragma unroll
                for (int kk = 0; kk < 4; kk++) {
                    int k = g * 4 + kk;
                    const float* wp = &Wn[(size_t)k * NN_ + c];
                    float2 w0 = *(const float2*)(wp);
                    float2 w1 = *(const float2*)(wp + 2);
                    float2 w2 = *(const float2*)(wp + 4);
                    float2 w3 = *(const float2*)(wp + 6);
                    #pragma unroll
                    for (int r = 0; r < 4; r++) {
                        float a = ((const float*)&av[r])[kk];
                        acc[r][0] += a * w0.x; acc[r][1] += a * w0.y;
                        acc[r][2] += a * w1.x; acc[r][3] += a * w1.y;
                        acc[r][4] += a * w2.x; acc[r][5] += a * w2.y;
                        acc[r][6] += a * w3.x; acc[r][7] += a * w3.y;
                    }
                }
            }
            float bb[8];
            #pragma unroll
            for (int q = 0; q < 8; q++) bb[q] = bn[c + q];
            #pragma unroll
            for (int r = 0; r < 4; r++) {
                size_t base = (size_t)(t0 + r0 + r) * NN_ + c;
                float v0 = acc[r][0]+bb[0], v1 = acc[r][1]+bb[1];
                float v2 = acc[r][2]+bb[2], v3 = acc[r][3]+bb[3];
                float v4 = acc[r][4]+bb[4], v5 = acc[r][5]+bb[5];
                float v6 = acc[r][6]+bb[6], v7 = acc[r][7]+bb[7];
                // NN_ ≡ 2 (mod 4): even local rows are 16B-aligned, odd 8B.
                // out_rn is write-only, streaming -> non-temporal stores.
                if ((r & 1) == 0) {
                    __builtin_nontemporal_store((vf4){v0,v1,v2,v3}, (vf4*)&out_rn[base]);
                    __builtin_nontemporal_store((vf4){v4,v5,v6,v7}, (vf4*)&out_rn[base + 4]);
                } else {
                    __builtin_nontemporal_store((vf2){v0,v1},       (vf2*)&out_rn[base]);
                    __builtin_nontemporal_store((vf4){v2,v3,v4,v5}, (vf4*)&out_rn[base + 2]);
                    __builtin_nontemporal_store((vf2){v6,v7},       (vf2*)&out_rn[base + 6]);
                }
            }
        } else {
            for (int e = 0; e < rem; e++) {
                float acc[4] = {0.f,0.f,0.f,0.f};
                for (int k = 0; k < 32; k++) {
                    float wv = Wn[(size_t)k * NN_ + c + e];
                    #pragma unroll
                    for (int r = 0; r < 4; r++) acc[r] += As[(r0 + r) * 32 + k] * wv;
                }
                float bv2 = bn[c + e];
                #pragma unroll
                for (int r = 0; r < 4; r++)
                    __builtin_nontemporal_store(acc[r] + bv2,
                        &out_rn[(size_t)(t0 + r0 + r) * NN_ + c + e]);
            }
        }
    } else {
        // ------------------- grouped gather + max/argmax/logsumexp
        int l = blockIdx.x;
        int jg = tid >> 5, b = tid & 31;
        float4 hv[8];
        {
            const float4* hp = (const float4*)&ho3[(size_t)l * 1024 + b * 32];
            #pragma unroll
            for (int q = 0; q < 8; q++) hv[q] = hp[q];
        }
        __syncthreads();
        float4 nd[8];
        #pragma unroll
        for (int q = 0; q < 8; q++) {
            float4 a = *(const float4*)&ob3[q * 4];
            #pragma unroll
            for (int dq = 0; dq < 8; dq++) {
                float4 h4 = hv[dq];
                float4 w0 = *(const float4*)&owT[(dq*4+0)*32 + q*4];
                float4 w1 = *(const float4*)&owT[(dq*4+1)*32 + q*4];
                float4 w2 = *(const float4*)&owT[(dq*4+2)*32 + q*4];
                float4 w3 = *(const float4*)&owT[(dq*4+3)*32 + q*4];
                a.x += h4.x*w0.x + h4.y*w1.x + h4.z*w2.x + h4.w*w3.x;
                a.y += h4.x*w0.y + h4.y*w1.y + h4.z*w2.y + h4.w*w3.y;
                a.z += h4.x*w0.z + h4.y*w1.z + h4.z*w2.z + h4.w*w3.z;
                a.w += h4.x*w0.w + h4.y*w1.w + h4.z*w2.w + h4.w*w3.w;
            }
            nd[q] = a;
        }
        float lm = -INFINITY, ls = 0.f;
        int jm = 0;
        const int* ip = &rni[l * 512];
        for (int jj = 0; jj < 64; jj++) {
            int j = jg * 64 + jj;
            int idx = ip[j];
            const float4* wr = (const float4*)&Wt[idx * 32];
            float s = bn[idx];
            #pragma unroll
            for (int q = 0; q < 8; q++) {
                float4 w4 = wr[q];
                s += nd[q].x*w4.x + nd[q].y*w4.y + nd[q].z*w4.z + nd[q].w*w4.w;
            }
            if (s > lm) { ls = ls * __expf(lm - s) + 1.f; lm = s; jm = j; }
            else        { ls += __expf(s - lm); }
        }
        pm[b * 8 + jg] = lm; psum[b * 8 + jg] = ls; pj[b * 8 + jg] = jm;
        __syncthreads();
        if (tid < 32) {
            int bb = tid;
            float M = pm[bb * 8], S = psum[bb * 8];
            int J = pj[bb * 8];
            for (int i = 1; i < 8; i++) {
                float m2 = pm[bb * 8 + i], s2 = psum[bb * 8 + i];
                if (m2 > M) { S = S * __expf(M - m2) + s2; M = m2; J = pj[bb * 8 + i]; }
                else        { S += s2 * __expf(m2 - M); }
            }
            int t = l * 32 + bb;
            marg[t]  = M + logf(S);
            rmax[t]  = M;
            rmaxi[t] = ip[J];
        }
    }
}

// ---------------------------------------------------------------- final stage
__global__ __launch_bounds__(256) void k_final(const float* __restrict__ marg,
                                               const float* __restrict__ rmax,
                                               const int* __restrict__ rmaxi,
                                               const int* __restrict__ pad,
                                               const float* __restrict__ vpot,
                                               float* __restrict__ out_norm,
                                               float* __restrict__ out_vmax,
                                               float* __restrict__ out_maxi) {
    int b = blockIdx.x, tid = threadIdx.x;
    __shared__ float me[191], xe[191];
    __shared__ int ie[191];
    __shared__ float vm[NV_];
    __shared__ float rbuf[4];
    if (tid < 191) {
        if (tid == 0) { me[0] = 0.f; xe[0] = 0.f; ie[0] = 0; }
        else {
            int t = (tid - 1) * 32 + b;
            me[tid] = marg[t]; xe[tid] = rmax[t]; ie[tid] = rmaxi[t];
        }
    }
    __syncthreads();
    for (int v = tid; v < NV_; v += 256) {
        float sm = 0.f, sx = 0.f;
        float vp = vpot[b * NV_ + v];
        #pragma unroll
        for (int i = 0; i < 6; i++) {
            int p = pad[v * 6 + i];
            sm += me[p]; sx += xe[p];
            out_maxi[(size_t)(b * NV_ + v) * 6 + i] = (float)ie[p];
        }
        vm[v] = sm + vp;
        out_vmax[b * NV_ + v] = sx + vp;
    }
    __syncthreads();
    float m = -INFINITY;
    for (int v = tid; v < NV_; v += 256) m = fmaxf(m, vm[v]);
    #pragma unroll
    for (int off = 32; off > 0; off >>= 1) m = fmaxf(m, __shfl_xor(m, off));
    if ((tid & 63) == 0) rbuf[tid >> 6] = m;
    __syncthreads();
    float M = fmaxf(fmaxf(rbuf[0], rbuf[1]), fmaxf(rbuf[2], rbuf[3]));
    __syncthreads();
    float s = 0.f;
    for (int v = tid; v < NV_; v += 256) s += __expf(vm[v] - M);
    #pragma unroll
    for (int off = 32; off > 0; off >>= 1) s += __shfl_xor(s, off);
    if ((tid & 63) == 0) rbuf[tid >> 6] = s;
    __syncthreads();
    if (tid == 0) out_norm[b] = M + logf(rbuf[0] + rbuf[1] + rbuf[2] + rbuf[3]);
}

// -------------------------------------------------------------------- launch
extern "C" void kernel_launch(void* const* d_in, const int* in_sizes, int n_in,
                              void* d_out, int out_size, void* d_ws, size_t ws_size,
                              hipStream_t stream) {
    const float* rep   = (const float*)d_in[0];
    const float* Wv    = (const float*)d_in[1];
    const float* bv    = (const float*)d_in[2];
    const float* Wr    = (const float*)d_in[3];
    const float* br    = (const float*)d_in[4];
    const float* ainw  = (const float*)d_in[5];
    const float* ainb  = (const float*)d_in[6];
    const float* aoutw = (const float*)d_in[7];
    const float* aoutb = (const float*)d_in[8];
    const float* Wn    = (const float*)d_in[9];
    const float* bn    = (const float*)d_in[10];
    const int*   rni   = (const int*)d_in[11];
    const int*   pad   = (const int*)d_in[12];
    float* out = (float*)d_out;
    float* ws  = (float*)d_ws;

    float* repT = ws + W_REPT;
    float* Wt   = ws + W_WT;
    float* pn   = ws + W_PN;
    float* pv   = ws + W_PV;
    float* n0   = ws + W_N0;
    float* hoA  = ws + W_HOA;
    float* hoB  = ws + W_HOB;
    float* marg = ws + W_MARG;
    float* rmx  = ws + W_RMAX;
    int*   rmi  = (int*)(ws + W_RMAXI);
    float* wc   = ws + W_WC;

    hipMemcpyAsync(out, rep, 32768 * sizeof(float), hipMemcpyDeviceToDevice, stream);
    k_tr_rep<<<128, 256, 0, stream>>>(rep, repT);
    k_pre<<<362, 256, 0, stream>>>(Wn, Wt, ainw, ainb, aoutw, aoutb, wc);
    k_gemm<<<dim3(103, 8), 256, 0, stream>>>(Wr, Wv, (const float4*)repT, pn, pv);
    k_reduce<<<823, 256, 0, stream>>>(pn, pv, br, bv, n0, out + O_VP);

    // layer 1: raw in-proj weights; layers 2,3: folded (prev out-proj ∘ in-proj)
    k_attn<<<128, 256, 0, stream>>>(n0,  ainw,      ainb,      hoA);
    k_attn<<<128, 256, 0, stream>>>(hoA, wc,        wc + 3072, hoB);
    k_attn<<<128, 256, 0, stream>>>(hoB, wc + 3168, wc + 6240, hoA);

    k_big<<<dim3(380, 24), 256, 0, stream>>>(hoA, aoutw + 2048, aoutb + 64,
                                             Wn, bn, Wt, rni,
                                             out + O_RN, marg, rmx, rmi);
    k_final<<<32, 256, 0, stream>>>(marg, rmx, rmi, pad, out + O_VP,
                                    out + O_NORM, out + O_VMAX, out + O_MAXI);
}

// Round 3
// 588.650 us; speedup vs baseline: 1.3071x; 1.3071x over previous
//
#include <hip/hip_runtime.h>
#include <math.h>

#define B_    32
#define REP_  1024
#define NV_   504
#define NR_   190
#define NN_   11538
#define MR_   6
#define HID_  32
#define NH_   4
#define HD_   8
#define MAXN_ 512

// d_out offsets (floats)
#define O_VP   32768
#define O_RN   48896
#define O_NORM 70199936
#define O_VMAX 70199968
#define O_MAXI 70216096

// ws offsets (floats)
#define W_REPT  0
#define W_WT    32768
#define W_PN    401984      // 8 * 194560
#define W_PV    1958464     // 8 * 16128
#define W_N0    2087488
#define W_HOB   2282048     // ho buffer B (194560)
#define W_HOA   2476608     // ho buffer A (194560)
#define W_MARG  2671168
#define W_RMAX  2677248
#define W_RMAXI 2683328     // int storage
#define W_WC    2689408     // 2 * (3072 + 96) combined attn-in weights

// ---------------------------------------------------------------- transposes
__global__ __launch_bounds__(256) void k_tr_rep(const float* __restrict__ rep,
                                                float* __restrict__ repT) {
    int gid = blockIdx.x * 256 + threadIdx.x;   // 32768 exact
    int b = gid & 31, k = gid >> 5;
    repT[gid] = rep[b * REP_ + k];
}

// blocks 0..360: 32x32 LDS tile transpose Wn (32 x 11538) -> Wt (11538 x 32)
// block 361: precompute combined attn weights for layers 2,3:
//   Wc[row][d] = sum_e iw[row][e] * ow[e][d];  bc[row] = iw[row]·ob + ib[row]
__global__ __launch_bounds__(256) void k_pre(const float* __restrict__ Wn,
                                             float* __restrict__ Wt,
                                             const float* __restrict__ ainw,
                                             const float* __restrict__ ainb,
                                             const float* __restrict__ aoutw,
                                             const float* __restrict__ aoutb,
                                             float* __restrict__ wc) {
    __shared__ float t[32][33];
    int tid = threadIdx.x;
    if (blockIdx.x < 361) {
        int n0 = blockIdx.x * 32;
        #pragma unroll
        for (int p = 0; p < 4; p++) {
            int idx = p * 256 + tid;
            int k = idx >> 5, n = idx & 31;
            int nn = n0 + n;
            t[k][n] = (nn < NN_) ? Wn[(size_t)k * NN_ + nn] : 0.f;
        }
        __syncthreads();
        #pragma unroll
        for (int p = 0; p < 4; p++) {
            int idx = p * 256 + tid;
            int n = idx >> 5, k = idx & 31;
            int nn = n0 + n;
            if (nn < NN_) Wt[nn * 32 + k] = t[k][n];
        }
    } else {
        #pragma unroll 1
        for (int layer = 0; layer < 2; layer++) {
            const float* iw  = ainw + (layer + 1) * 3072;   // in_w of next layer
            const float* ib  = ainb + (layer + 1) * 96;
            const float* ow  = aoutw + layer * 1024;        // out_w of this layer
            const float* obv = aoutb + layer * 32;
            float* W = wc + layer * 3168;
            for (int idx = tid; idx < 3072; idx += 256) {
                int row = idx >> 5, d = idx & 31;
                float s = 0.f;
                #pragma unroll
                for (int e = 0; e < 32; e++) s += iw[row * 32 + e] * ow[e * 32 + d];
                W[idx] = s;
            }
            if (tid < 96) {
                float s = ib[tid];
                #pragma unroll
                for (int e = 0; e < 32; e++) s += iw[tid * 32 + e] * obv[e];
                W[3072 + tid] = s;
            }
        }
    }
}

// ------------------------------------------------- rep GEMMs (k-split partials)
// bx < 95 : node columns (6080);  bx >= 95 : v_potential columns (504)
__global__ __launch_bounds__(256) void k_gemm(const float* __restrict__ Wr,
                                              const float* __restrict__ Wv,
                                              const float4* __restrict__ repT4,
                                              float* __restrict__ pn,
                                              float* __restrict__ pv) {
    int bx = blockIdx.x;
    int lane = threadIdx.x & 63;
    int bg = threadIdx.x >> 6;
    int k0 = blockIdx.y * 128;
    int rbase = k0 * 8 + bg * 2;
    float acc[8] = {0.f,0.f,0.f,0.f,0.f,0.f,0.f,0.f};
    if (bx < 95) {
        int c = bx * 64 + lane;
        const float* w = Wr + (size_t)k0 * 6080 + c;
        #pragma unroll 4
        for (int k = 0; k < 128; k++) {
            float wv = w[(size_t)k * 6080];
            float4 ra = repT4[rbase + k * 8];
            float4 rb = repT4[rbase + k * 8 + 1];
            acc[0] += ra.x * wv; acc[1] += ra.y * wv; acc[2] += ra.z * wv; acc[3] += ra.w * wv;
            acc[4] += rb.x * wv; acc[5] += rb.y * wv; acc[6] += rb.z * wv; acc[7] += rb.w * wv;
        }
        size_t base = (size_t)blockIdx.y * 194560 + (size_t)(bg * 8) * 6080 + c;
        #pragma unroll
        for (int i = 0; i < 8; i++) pn[base + (size_t)i * 6080] = acc[i];
    } else {
        int c = (bx - 95) * 64 + lane;
        if (c >= NV_) return;
        const float* w = Wv + (size_t)k0 * NV_ + c;
        #pragma unroll 4
        for (int k = 0; k < 128; k++) {
            float wv = w[(size_t)k * NV_];
            float4 ra = repT4[rbase + k * 8];
            float4 rb = repT4[rbase + k * 8 + 1];
            acc[0] += ra.x * wv; acc[1] += ra.y * wv; acc[2] += ra.z * wv; acc[3] += ra.w * wv;
            acc[4] += rb.x * wv; acc[5] += rb.y * wv; acc[6] += rb.z * wv; acc[7] += rb.w * wv;
        }
        size_t base = (size_t)blockIdx.y * 16128 + (size_t)(bg * 8) * NV_ + c;
        #pragma unroll
        for (int i = 0; i < 8; i++) pv[base + (size_t)i * NV_] = acc[i];
    }
}

__global__ __launch_bounds__(256) void k_reduce(const float* __restrict__ pn,
                                                const float* __restrict__ pv,
                                                const float* __restrict__ br,
                                                const float* __restrict__ bv,
                                                float* __restrict__ node0,
                                                float* __restrict__ vpot) {
    int bid = blockIdx.x, tid = threadIdx.x;
    if (bid < 760) {
        int gid = bid * 256 + tid;                 // enumerates [b][c], c<6080
        int b = gid / 6080, c = gid - b * 6080;
        float s = br[c];
        #pragma unroll
        for (int kz = 0; kz < 8; kz++) s += pn[kz * 194560 + gid];
        node0[(c >> 5) * 1024 + b * 32 + (c & 31)] = s;
    } else {
        int gid = (bid - 760) * 256 + tid;         // enumerates [b][v], v<504
        int v = gid % NV_;
        float s = bv[v];
        #pragma unroll
        for (int kz = 0; kz < 8; kz++) s += pv[kz * 16128 + gid];
        vpot[gid] = s;
    }
}

// ---------------------------------------------------------------- attention
// One block per (b,h). Input xin is [l][b][e] (either node0 or previous ho);
// winw/winb are either the raw layer-0 in-proj or the folded (in·out) weights,
// so the out-projection kernels disappear entirely.
__global__ __launch_bounds__(256) void k_attn(const float* __restrict__ xin,
                                              const float* __restrict__ winw,
                                              const float* __restrict__ winb,
                                              float* __restrict__ ho) {
    int b = blockIdx.x >> 2, h = blockIdx.x & 3;
    int tid = threadIdx.x;
    __shared__ __align__(16) float qs[192 * 12];
    __shared__ __align__(16) float ks[192 * 12];
    __shared__ __align__(16) float vs[192 * 12];
    __shared__ __align__(16) float pmS[4 * 192];
    __shared__ __align__(16) float psS[4 * 192];
    __shared__ __align__(16) float poS[4 * 192 * 8];

    if (tid < NR_) {
        const float* xr = xin + tid * 1024 + b * 32;
        float4 xv[8];
        #pragma unroll
        for (int q = 0; q < 8; q++) xv[q] = *(const float4*)(xr + q * 4);
        #pragma unroll 1
        for (int part = 0; part < 3; part++) {
            float* dst = (part == 0) ? qs : (part == 1) ? ks : vs;
            #pragma unroll 1
            for (int jj = 0; jj < 8; jj++) {
                int row = part * 32 + h * 8 + jj;      // wave-uniform
                const float* wr = winw + row * 32;
                float s = winb[row];
                #pragma unroll
                for (int q = 0; q < 8; q++) {
                    s += xv[q].x * wr[q*4+0] + xv[q].y * wr[q*4+1] +
                         xv[q].z * wr[q*4+2] + xv[q].w * wr[q*4+3];
                }
                dst[tid * 12 + jj] = s;
            }
        }
    }
    __syncthreads();

    int wave = tid >> 6, lane = tid & 63;
    int m0 = wave * 48;
    int m1 = (m0 + 48 < NR_) ? (m0 + 48) : NR_;
    float4 qa[3], qb[3];
    #pragma unroll
    for (int i = 0; i < 3; i++) {
        int l = lane + 64 * i;
        if (l < NR_) {
            qa[i] = *(const float4*)&qs[l * 12];
            qb[i] = *(const float4*)&qs[l * 12 + 4];
        } else {
            qa[i] = make_float4(0.f,0.f,0.f,0.f);
            qb[i] = make_float4(0.f,0.f,0.f,0.f);
        }
    }
    float mM[3] = {-INFINITY, -INFINITY, -INFINITY};
    float sS[3] = {0.f, 0.f, 0.f};
    float o[3][8];
    #pragma unroll
    for (int i = 0; i < 3; i++)
        #pragma unroll
        for (int d = 0; d < 8; d++) o[i][d] = 0.f;
    const float scale = 0.3535533905932738f;
    for (int mm = m0; mm < m1; mm++) {
        float4 ka = *(const float4*)&ks[mm * 12];
        float4 kb = *(const float4*)&ks[mm * 12 + 4];
        float4 va = *(const float4*)&vs[mm * 12];
        float4 vb = *(const float4*)&vs[mm * 12 + 4];
        #pragma unroll
        for (int i = 0; i < 3; i++) {
            float sc = (qa[i].x*ka.x + qa[i].y*ka.y + qa[i].z*ka.z + qa[i].w*ka.w +
                        qb[i].x*kb.x + qb[i].y*kb.y + qb[i].z*kb.z + qb[i].w*kb.w) * scale;
            if (sc > mM[i]) {
                float al = __expf(mM[i] - sc);   // exp(-inf)=0 on first hit
                sS[i] = sS[i] * al + 1.f;
                mM[i] = sc;
                o[i][0] = o[i][0]*al + va.x; o[i][1] = o[i][1]*al + va.y;
                o[i][2] = o[i][2]*al + va.z; o[i][3] = o[i][3]*al + va.w;
                o[i][4] = o[i][4]*al + vb.x; o[i][5] = o[i][5]*al + vb.y;
                o[i][6] = o[i][6]*al + vb.z; o[i][7] = o[i][7]*al + vb.w;
            } else {
                float p = __expf(sc - mM[i]);
                sS[i] += p;
                o[i][0] += p*va.x; o[i][1] += p*va.y; o[i][2] += p*va.z; o[i][3] += p*va.w;
                o[i][4] += p*vb.x; o[i][5] += p*vb.y; o[i][6] += p*vb.z; o[i][7] += p*vb.w;
            }
        }
    }
    #pragma unroll
    for (int i = 0; i < 3; i++) {
        int slot = wave * 192 + lane + 64 * i;
        pmS[slot] = mM[i];
        psS[slot] = sS[i];
        *(float4*)&poS[slot * 8]     = make_float4(o[i][0], o[i][1], o[i][2], o[i][3]);
        *(float4*)&poS[slot * 8 + 4] = make_float4(o[i][4], o[i][5], o[i][6], o[i][7]);
    }
    __syncthreads();

    if (tid < NR_) {
        float M = pmS[tid], S = psS[tid];
        float4 oa = *(const float4*)&poS[tid * 8];
        float4 ob = *(const float4*)&poS[tid * 8 + 4];
        #pragma unroll
        for (int w = 1; w < 4; w++) {
            int slot = w * 192 + tid;
            float m2 = pmS[slot], s2 = psS[slot];
            float4 pa = *(const float4*)&poS[slot * 8];
            float4 pb = *(const float4*)&poS[slot * 8 + 4];
            if (m2 > M) {
                float al = __expf(M - m2);
                S = S * al + s2;
                oa.x = oa.x*al + pa.x; oa.y = oa.y*al + pa.y; oa.z = oa.z*al + pa.z; oa.w = oa.w*al + pa.w;
                ob.x = ob.x*al + pb.x; ob.y = ob.y*al + pb.y; ob.z = ob.z*al + pb.z; ob.w = ob.w*al + pb.w;
                M = m2;
            } else {
                float p = __expf(m2 - M);
                S += s2 * p;
                oa.x += p*pa.x; oa.y += p*pa.y; oa.z += p*pa.z; oa.w += p*pa.w;
                ob.x += p*pb.x; ob.y += p*pb.y; ob.z += p*pb.z; ob.w += p*pb.w;
            }
        }
        float inv = 1.f / S;
        float* hp = ho + tid * 1024 + b * 32 + h * 8;
        *(float4*)hp       = make_float4(oa.x*inv, oa.y*inv, oa.z*inv, oa.w*inv);
        *(float4*)(hp + 4) = make_float4(ob.x*inv, ob.y*inv, ob.z*inv, ob.w*inv);
    }
}

// ----------------------------------------- fused back-end: rnpot + grouped
// Layer-3 out-proj folded in (node row R = ho3[R*32..] @ ow3 + ob3, since
// node rows are (l,b) pairs and ho3 is contiguous in that order).
// 1D grid of 190 + 95*46 blocks:
//   bid < 190            : grouped gather for role l = bid (launched first;
//                          latency-bound long poles start early)
//   bid >= 190           : GEMM tile, g = bid-190, rows (g%95)*64..+63,
//                          cols (g/95)*256..+255.
// Wn panel (32x256, 32 KB) staged in LDS once per block -> inner loop is
// 5 LDS reads + 64 FMA per k: VALU-bound, no L2 latency on critical path
// (R1's direct-load version stalled at VALUBusy=22%). NO nontemporal stores
// (R2: NT on sub-line patterns doubled WRITE_SIZE via partial-line RMW).
__global__ __launch_bounds__(256, 4) void k_big(const float* __restrict__ ho3,
                                                const float* __restrict__ ow3,
                                                const float* __restrict__ ob3,
                                                const float* __restrict__ Wn,
                                                const float* __restrict__ bn,
                                                const float* __restrict__ Wt,
                                                const int* __restrict__ rni,
                                                float* __restrict__ out_rn,
                                                float* __restrict__ marg,
                                                float* __restrict__ rmax,
                                                int* __restrict__ rmaxi) {
    int bid = blockIdx.x;
    int tid = threadIdx.x;
    __shared__ __align__(16) float smem[8192 + 2048 + 1024 + 32];
    float* Ws  = smem;              // [32][256] Wn panel (GEMM path only)
    float* Ask = smem + 8192;       // [32][64]  node tile, k-major (GEMM only)
    float* ows = smem + 10240;      // [32][32]  ow3 row-major (both paths)
    float* obs = smem + 11264;      // [32]      ob3 (both paths)

    for (int i = tid; i < 1024; i += 256) ows[i] = ow3[i];
    if (tid < 32) obs[tid] = ob3[tid];

    if (bid >= 190) {
        int g  = bid - 190;
        int bx = g % 95;
        int by = g / 95;
        int t0 = bx * 64;
        int c0 = by * 256;
        bool tail = (c0 + 256 > NN_);

        // ---- stage Wn panel: 32 rows x 256 cols (float2: rows are 8B-aligned)
        #pragma unroll
        for (int p = 0; p < 16; p++) {
            int idx = p * 256 + tid;
            int k  = idx >> 7;              // 0..31
            int c2 = (idx & 127) * 2;       // 0..254
            int cg = c0 + c2;
            float2 v = (cg < NN_) ? *(const float2*)&Wn[(size_t)k * NN_ + cg]
                                  : make_float2(0.f, 0.f);
            *(float2*)&Ws[k * 256 + c2] = v;
        }
        __syncthreads();   // ows ready (needed by recompute below)

        // ---- node tile recompute -> Ask[k][r] (k-major for broadcast reads)
        {
            int r = tid >> 2, hq = tid & 3;
            const float4* hp = (const float4*)&ho3[(size_t)(t0 + r) * 32];
            float4 hv[8];
            #pragma unroll
            for (int q = 0; q < 8; q++) hv[q] = hp[q];
            #pragma unroll
            for (int i = 0; i < 8; i++) {
                int h = hq * 8 + i;
                float s = obs[h];
                #pragma unroll
                for (int d4 = 0; d4 < 8; d4++) {
                    float4 h4 = hv[d4];
                    float4 w = *(const float4*)&ows[h * 32 + d4 * 4];
                    s += h4.x*w.x + h4.y*w.y + h4.z*w.z + h4.w*w.w;
                }
                Ask[h * 64 + r] = s;
            }
        }
        __syncthreads();

        // ---- 64 x 256 GEMM tile from LDS
        int wave = tid >> 6, lane = tid & 63;
        int r0 = wave * 16;
        int cL = lane * 4;
        int c  = c0 + cL;
        float acc[16][4];
        #pragma unroll
        for (int r = 0; r < 16; r++)
            #pragma unroll
            for (int q = 0; q < 4; q++) acc[r][q] = 0.f;

        #pragma unroll 4
        for (int k = 0; k < 32; k++) {
            float4 wv = *(const float4*)&Ws[k * 256 + cL];
            float4 av[4];
            av[0] = *(const float4*)&Ask[k * 64 + r0];
            av[1] = *(const float4*)&Ask[k * 64 + r0 + 4];
            av[2] = *(const float4*)&Ask[k * 64 + r0 + 8];
            av[3] = *(const float4*)&Ask[k * 64 + r0 + 12];
            const float* ap = (const float*)av;
            #pragma unroll
            for (int r = 0; r < 16; r++) {
                float a = ap[r];
                acc[r][0] += a * wv.x; acc[r][1] += a * wv.y;
                acc[r][2] += a * wv.z; acc[r][3] += a * wv.w;
            }
        }

        if (!tail) {
            float4 bb = *(const float4*)&bn[c];
            #pragma unroll
            for (int r = 0; r < 16; r++) {
                size_t base = (size_t)(t0 + r0 + r) * NN_ + c;
                float v0 = acc[r][0] + bb.x, v1 = acc[r][1] + bb.y;
                float v2 = acc[r][2] + bb.z, v3 = acc[r][3] + bb.w;
                // NN_ ≡ 2 (mod 4): even rows 16B-aligned, odd rows 8B.
                if ((r & 1) == 0) {
                    *(float4*)&out_rn[base] = make_float4(v0, v1, v2, v3);
                } else {
                    *(float2*)&out_rn[base]     = make_float2(v0, v1);
                    *(float2*)&out_rn[base + 2] = make_float2(v2, v3);
                }
            }
        } else {
            #pragma unroll
            for (int r = 0; r < 16; r++) {
                size_t base = (size_t)(t0 + r0 + r) * NN_;
                #pragma unroll
                for (int q = 0; q < 4; q++) {
                    if (c + q < NN_)
                        out_rn[base + c + q] = acc[r][q] + bn[c + q];
                }
            }
        }
    } else {
        // ------------------- grouped gather + max/argmax/logsumexp
        int l = bid;
        int jg = tid >> 5, b = tid & 31;
        float* pm   = smem;                 // overlays Ws (unused here)
        float* psum = smem + 256;
        int*   pj   = (int*)(smem + 512);
        float4 hv[8];
        {
            const float4* hp = (const float4*)&ho3[(size_t)l * 1024 + b * 32];
            #pragma unroll
            for (int q = 0; q < 8; q++) hv[q] = hp[q];
        }
        __syncthreads();   // ows/obs ready
        float4 nd[8];
        #pragma unroll
        for (int q = 0; q < 8; q++) {
            float s[4];
            #pragma unroll
            for (int j = 0; j < 4; j++) {
                int h = q * 4 + j;
                float a = obs[h];
                #pragma unroll
                for (int d4 = 0; d4 < 8; d4++) {
                    float4 h4 = hv[d4];
                    float4 w = *(const float4*)&ows[h * 32 + d4 * 4];
                    a += h4.x*w.x + h4.y*w.y + h4.z*w.z + h4.w*w.w;
                }
                s[j] = a;
            }
            nd[q] = make_float4(s[0], s[1], s[2], s[3]);
        }
        float lm = -INFINITY, ls = 0.f;
        int jm = 0;
        const int* ip = &rni[l * 512];
        for (int jj = 0; jj < 64; jj++) {
            int j = jg * 64 + jj;
            int idx = ip[j];
            const float4* wr = (const float4*)&Wt[idx * 32];
            float s = bn[idx];
            #pragma unroll
            for (int q = 0; q < 8; q++) {
                float4 w4 = wr[q];
                s += nd[q].x*w4.x + nd[q].y*w4.y + nd[q].z*w4.z + nd[q].w*w4.w;
            }
            if (s > lm) { ls = ls * __expf(lm - s) + 1.f; lm = s; jm = j; }
            else        { ls += __expf(s - lm); }
        }
        pm[b * 8 + jg] = lm; psum[b * 8 + jg] = ls; pj[b * 8 + jg] = jm;
        __syncthreads();
        if (tid < 32) {
            int bb = tid;
            float M = pm[bb * 8], S = psum[bb * 8];
            int J = pj[bb * 8];
            for (int i = 1; i < 8; i++) {
                float m2 = pm[bb * 8 + i], s2 = psum[bb * 8 + i];
                if (m2 > M) { S = S * __expf(M - m2) + s2; M = m2; J = pj[bb * 8 + i]; }
                else        { S += s2 * __expf(m2 - M); }
            }
            int t = l * 32 + bb;
            marg[t]  = M + logf(S);
            rmax[t]  = M;
            rmaxi[t] = ip[J];
        }
    }
}

// ---------------------------------------------------------------- final stage
__global__ __launch_bounds__(256) void k_final(const float* __restrict__ marg,
                                               const float* __restrict__ rmax,
                                               const int* __restrict__ rmaxi,
                                               const int* __restrict__ pad,
                                               const float* __restrict__ vpot,
                                               float* __restrict__ out_norm,
                                               float* __restrict__ out_vmax,
                                               float* __restrict__ out_maxi) {
    int b = blockIdx.x, tid = threadIdx.x;
    __shared__ float me[191], xe[191];
    __shared__ int ie[191];
    __shared__ float vm[NV_];
    __shared__ float rbuf[4];
    if (tid < 191) {
        if (tid == 0) { me[0] = 0.f; xe[0] = 0.f; ie[0] = 0; }
        else {
            int t = (tid - 1) * 32 + b;
            me[tid] = marg[t]; xe[tid] = rmax[t]; ie[tid] = rmaxi[t];
        }
    }
    __syncthreads();
    for (int v = tid; v < NV_; v += 256) {
        float sm = 0.f, sx = 0.f;
        float vp = vpot[b * NV_ + v];
        #pragma unroll
        for (int i = 0; i < 6; i++) {
            int p = pad[v * 6 + i];
            sm += me[p]; sx += xe[p];
            out_maxi[(size_t)(b * NV_ + v) * 6 + i] = (float)ie[p];
        }
        vm[v] = sm + vp;
        out_vmax[b * NV_ + v] = sx + vp;
    }
    __syncthreads();
    float m = -INFINITY;
    for (int v = tid; v < NV_; v += 256) m = fmaxf(m, vm[v]);
    #pragma unroll
    for (int off = 32; off > 0; off >>= 1) m = fmaxf(m, __shfl_xor(m, off));
    if ((tid & 63) == 0) rbuf[tid >> 6] = m;
    __syncthreads();
    float M = fmaxf(fmaxf(rbuf[0], rbuf[1]), fmaxf(rbuf[2], rbuf[3]));
    __syncthreads();
    float s = 0.f;
    for (int v = tid; v < NV_; v += 256) s += __expf(vm[v] - M);
    #pragma unroll
    for (int off = 32; off > 0; off >>= 1) s += __shfl_xor(s, off);
    if ((tid & 63) == 0) rbuf[tid >> 6] = s;
    __syncthreads();
    if (tid == 0) out_norm[b] = M + logf(rbuf[0] + rbuf[1] + rbuf[2] + rbuf[3]);
}

// -------------------------------------------------------------------- launch
extern "C" void kernel_launch(void* const* d_in, const int* in_sizes, int n_in,
                              void* d_out, int out_size, void* d_ws, size_t ws_size,
                              hipStream_t stream) {
    const float* rep   = (const float*)d_in[0];
    const float* Wv    = (const float*)d_in[1];
    const float* bv    = (const float*)d_in[2];
    const float* Wr    = (const float*)d_in[3];
    const float* br    = (const float*)d_in[4];
    const float* ainw  = (const float*)d_in[5];
    const float* ainb  = (const float*)d_in[6];
    const float* aoutw = (const float*)d_in[7];
    const float* aoutb = (const float*)d_in[8];
    const float* Wn    = (const float*)d_in[9];
    const float* bn    = (const float*)d_in[10];
    const int*   rni   = (const int*)d_in[11];
    const int*   pad   = (const int*)d_in[12];
    float* out = (float*)d_out;
    float* ws  = (float*)d_ws;

    float* repT = ws + W_REPT;
    float* Wt   = ws + W_WT;
    float* pn   = ws + W_PN;
    float* pv   = ws + W_PV;
    float* n0   = ws + W_N0;
    float* hoA  = ws + W_HOA;
    float* hoB  = ws + W_HOB;
    float* marg = ws + W_MARG;
    float* rmx  = ws + W_RMAX;
    int*   rmi  = (int*)(ws + W_RMAXI);
    float* wc   = ws + W_WC;

    hipMemcpyAsync(out, rep, 32768 * sizeof(float), hipMemcpyDeviceToDevice, stream);
    k_tr_rep<<<128, 256, 0, stream>>>(rep, repT);
    k_pre<<<362, 256, 0, stream>>>(Wn, Wt, ainw, ainb, aoutw, aoutb, wc);
    k_gemm<<<dim3(103, 8), 256, 0, stream>>>(Wr, Wv, (const float4*)repT, pn, pv);
    k_reduce<<<823, 256, 0, stream>>>(pn, pv, br, bv, n0, out + O_VP);

    // layer 1: raw in-proj weights; layers 2,3: folded (prev out-proj ∘ in-proj)
    k_attn<<<128, 256, 0, stream>>>(n0,  ainw,      ainb,      hoA);
    k_attn<<<128, 256, 0, stream>>>(hoA, wc,        wc + 3072, hoB);
    k_attn<<<128, 256, 0, stream>>>(hoB, wc + 3168, wc + 6240, hoA);

    // 190 gather blocks first, then 95x46 GEMM tiles
    k_big<<<190 + 95 * 46, 256, 0, stream>>>(hoA, aoutw + 2048, aoutb + 64,
                                             Wn, bn, Wt, rni,
                                             out + O_RN, marg, rmx, rmi);
    k_final<<<32, 256, 0, stream>>>(marg, rmx, rmi, pad, out + O_VP,
                                    out + O_NORM, out + O_VMAX, out + O_MAXI);
}